// Round 1
// baseline (1041.218 us; speedup 1.0000x reference)
//
#include <hip/hip_runtime.h>
#include <stdint.h>

#define N_NODES 50000
#define N_EDGES 800000
#define NFEAT 512
#define NHID 128
#define NCLASS 40

typedef __attribute__((ext_vector_type(8))) __bf16 bf16x8;
typedef __attribute__((ext_vector_type(4))) float f32x4;

__device__ __forceinline__ uint16_t f2b(float f) {
  uint32_t x = __float_as_uint(f);
  uint32_t r = (x + 0x7fffu + ((x >> 16) & 1u)) >> 16;
  return (uint16_t)r;
}
__device__ __forceinline__ float b2f(uint16_t u) {
  return __uint_as_float(((uint32_t)u) << 16);
}

// ---------------- cast x (fp32 -> bf16), 8 elems/thread ----------------
__global__ void k_cast_x(const float* __restrict__ x, uint16_t* __restrict__ xb, int n8) {
  int i = blockIdx.x * blockDim.x + threadIdx.x;
  if (i >= n8) return;
  const float4* p = (const float4*)x + (size_t)i * 2;
  float4 a = p[0], b = p[1];
  union { uint16_t u[8]; uint4 v; } o;
  o.u[0] = f2b(a.x); o.u[1] = f2b(a.y); o.u[2] = f2b(a.z); o.u[3] = f2b(a.w);
  o.u[4] = f2b(b.x); o.u[5] = f2b(b.y); o.u[6] = f2b(b.z); o.u[7] = f2b(b.w);
  ((uint4*)xb)[i] = o.v;
}

// ---------------- weight prep: WT1[256][512] = [W1 | Wr1]^T bf16 ----------------
__global__ void k_prep_w1(const float* __restrict__ W1, const float* __restrict__ Wr1,
                          uint16_t* __restrict__ WT) {
  int idx = blockIdx.x * 256 + threadIdx.x;  // 256*512
  if (idx >= 256 * 512) return;
  int n = idx >> 9, k = idx & 511;
  float v = (n < 128) ? W1[(size_t)k * 128 + n] : Wr1[(size_t)k * 128 + (n - 128)];
  WT[idx] = f2b(v);
}

// ---------------- weight prep: WT2[128][256] = [W2 | Wr2 | 0pad]^T bf16 ----------------
__global__ void k_prep_w2(const float* __restrict__ W2, const float* __restrict__ Wr2,
                          uint16_t* __restrict__ WT) {
  int idx = blockIdx.x * 256 + threadIdx.x;  // 128*256
  if (idx >= 128 * 256) return;
  int n = idx >> 8, k = idx & 255;
  float v = 0.f;
  if (n < 40) v = W2[(size_t)k * 40 + n];
  else if (n < 80) v = Wr2[(size_t)k * 40 + (n - 40)];
  WT[idx] = f2b(v);
}

// ---------------- MFMA GEMM, m97 structure: 128x128 tile, 4 waves 2x2, BK=64 ----------------
// C = A[M,K] * BT[N,K]^T.  EPI=1: n<128 -> S1b bf16; n>=128 -> h[:,n] = bf16(acc+br1[n-128])
//                          EPI=2: n<40 -> S2b bf16; 40<=n<80 -> oacc = acc+b2+br2
template <int K, int EPI>
__global__ __launch_bounds__(256, 2) void k_gemm(
    const uint16_t* __restrict__ A, const uint16_t* __restrict__ BT, int M,
    uint16_t* __restrict__ out_bf_a, uint16_t* __restrict__ out_bf_b,
    float* __restrict__ out_f, const float* __restrict__ bias_a,
    const float* __restrict__ bias_b) {
  __shared__ uint16_t Al[128 * 64];
  __shared__ uint16_t Bl[128 * 64];
  const int tid = threadIdx.x;
  const int w = tid >> 6, lane = tid & 63;
  const int wm = w >> 1, wn = w & 1;
  const int m0 = blockIdx.x * 128;
  const int n0 = blockIdx.y * 128;

  f32x4 acc[4][4];
#pragma unroll
  for (int t = 0; t < 4; t++)
#pragma unroll
    for (int u = 0; u < 4; u++) acc[t][u] = (f32x4)0.f;

  const int lrow = lane >> 3;  // 0..7 : row within 8-row staging chunk
  const int lcol = lane & 7;   // 0..7 : 16B slot within 128B row

  for (int kb = 0; kb < K / 64; ++kb) {
    __syncthreads();
    const int k0 = kb * 64;
#pragma unroll
    for (int i = 0; i < 4; i++) {
      int rr = (w * 4 + i) * 8 + lrow;
      int ra = m0 + rr;
      if (ra >= M) ra = M - 1;  // clamp tail rows (stores are guarded)
      const uint16_t* gA = A + (size_t)ra * K + k0 + lcol * 8;
      __builtin_amdgcn_global_load_lds(
          (const __attribute__((address_space(1))) void*)gA,
          (__attribute__((address_space(3))) void*)&Al[(w * 4 + i) * 512], 16, 0, 0);
      int rb = n0 + rr;  // N is exact multiple of 128
      const uint16_t* gB = BT + (size_t)rb * K + k0 + lcol * 8;
      __builtin_amdgcn_global_load_lds(
          (const __attribute__((address_space(1))) void*)gB,
          (__attribute__((address_space(3))) void*)&Bl[(w * 4 + i) * 512], 16, 0, 0);
    }
    __syncthreads();  // compiler drains vmcnt(0) here (m97 pattern)
#pragma unroll
    for (int s = 0; s < 2; s++) {
      bf16x8 av[4], bv[4];
#pragma unroll
      for (int t = 0; t < 4; t++)
        av[t] = *(const bf16x8*)&Al[(wm * 64 + t * 16 + (lane & 15)) * 64 + s * 32 + (lane >> 4) * 8];
#pragma unroll
      for (int u = 0; u < 4; u++)
        bv[u] = *(const bf16x8*)&Bl[(wn * 64 + u * 16 + (lane & 15)) * 64 + s * 32 + (lane >> 4) * 8];
#pragma unroll
      for (int t = 0; t < 4; t++)
#pragma unroll
        for (int u = 0; u < 4; u++)
          acc[t][u] = __builtin_amdgcn_mfma_f32_16x16x32_bf16(av[t], bv[u], acc[t][u], 0, 0, 0);
    }
  }

  // epilogue: C/D layout col=lane&15, row=quad*4+reg (m89/m91-verified)
  const int cl = lane & 15, rq = lane >> 4;
#pragma unroll
  for (int t = 0; t < 4; t++) {
#pragma unroll
    for (int u = 0; u < 4; u++) {
#pragma unroll
      for (int r = 0; r < 4; r++) {
        int m = m0 + wm * 64 + t * 16 + rq * 4 + r;
        int n = n0 + wn * 64 + u * 16 + cl;
        if (m >= M) continue;
        float v = acc[t][u][r];
        if constexpr (EPI == 1) {
          if (n < 128)
            out_bf_a[(size_t)m * 128 + n] = f2b(v);  // S1 = x@W1 (bias b1 added post-spmm)
          else
            out_bf_b[(size_t)m * 256 + n] = f2b(v + bias_a[n - 128]);  // h right = x@Wr1+br1
        } else {
          if (n < 40)
            out_bf_a[(size_t)m * 40 + n] = f2b(v);  // S2 = h@W2
          else if (n < 80)
            out_f[(size_t)m * 40 + (n - 40)] = v + bias_a[n - 40] + bias_b[n - 40];  // h@Wr2+br2+b2
        }
      }
    }
  }
}

// ---------------- SpMM1: gc1[dst] += val * S1b[src], 128 feats, wave/edge ----------------
__global__ void k_spmm1(const int* __restrict__ src, const int* __restrict__ dst,
                        const float* __restrict__ val, const uint16_t* __restrict__ S1b,
                        float* __restrict__ gc1) {
  int e = blockIdx.x * 4 + (threadIdx.x >> 6);
  if (e >= N_EDGES) return;
  int lane = threadIdx.x & 63;
  int s = src[e], d = dst[e];
  float v = val[e];
  uint32_t p = *(const uint32_t*)(S1b + (size_t)s * 128 + lane * 2);
  float lo = b2f((uint16_t)(p & 0xffffu));
  float hi = b2f((uint16_t)(p >> 16));
  unsafeAtomicAdd(&gc1[(size_t)d * 128 + lane * 2], v * lo);
  unsafeAtomicAdd(&gc1[(size_t)d * 128 + lane * 2 + 1], v * hi);
}

// ---------------- h left half: relu(gc1 + b1) -> bf16 ----------------
__global__ void k_h(const float* __restrict__ gc1, const float* __restrict__ b1,
                    uint16_t* __restrict__ h) {
  int idx = blockIdx.x * 256 + threadIdx.x;
  if (idx >= N_NODES * 128) return;
  int m = idx >> 7, f = idx & 127;
  float v = gc1[idx] + b1[f];
  h[(size_t)m * 256 + f] = f2b(v > 0.f ? v : 0.f);
}

// ---------------- SpMM2: oacc[dst] += val * S2b[src], 40 feats, wave/edge ----------------
__global__ void k_spmm2(const int* __restrict__ src, const int* __restrict__ dst,
                        const float* __restrict__ val, const uint16_t* __restrict__ S2b,
                        float* __restrict__ oacc) {
  int e = blockIdx.x * 4 + (threadIdx.x >> 6);
  if (e >= N_EDGES) return;
  int lane = threadIdx.x & 63;
  if (lane >= 40) return;
  int s = src[e], d = dst[e];
  float v = val[e];
  float x = b2f(S2b[(size_t)s * 40 + lane]);
  unsafeAtomicAdd(&oacc[(size_t)d * 40 + lane], v * x);
}

// ---------------- log_softmax over 40 classes, wave/row ----------------
__global__ void k_lsm(const float* __restrict__ oacc, float* __restrict__ out) {
  int m = blockIdx.x * 4 + (threadIdx.x >> 6);
  if (m >= N_NODES) return;
  int lane = threadIdx.x & 63;
  float v = (lane < 40) ? oacc[(size_t)m * 40 + lane] : -1e30f;
  float mv = v;
#pragma unroll
  for (int o = 32; o; o >>= 1) {
    float t = __shfl_xor(mv, o, 64);
    mv = mv > t ? mv : t;
  }
  float e = (lane < 40) ? __expf(v - mv) : 0.f;
  float se = e;
#pragma unroll
  for (int o = 32; o; o >>= 1) se += __shfl_xor(se, o, 64);
  if (lane < 40) out[(size_t)m * 40 + lane] = v - mv - __logf(se);
}

extern "C" void kernel_launch(void* const* d_in, const int* in_sizes, int n_in,
                              void* d_out, int out_size, void* d_ws, size_t ws_size,
                              hipStream_t stream) {
  const float* x = (const float*)d_in[0];
  const int* esrc = (const int*)d_in[1];
  const int* edst = (const int*)d_in[2];
  const float* eval = (const float*)d_in[3];
  const float* W1 = (const float*)d_in[4];
  const float* b1 = (const float*)d_in[5];
  const float* Wr1 = (const float*)d_in[6];
  const float* br1 = (const float*)d_in[7];
  const float* W2 = (const float*)d_in[8];
  const float* b2 = (const float*)d_in[9];
  const float* Wr2 = (const float*)d_in[10];
  const float* br2 = (const float*)d_in[11];
  float* out = (float*)d_out;

  char* ws = (char*)d_ws;
  uint16_t* xb  = (uint16_t*)(ws);                   // 51,200,000 B
  uint16_t* S1b = (uint16_t*)(ws + 51200000);        // 12,800,000 B
  uint16_t* h   = (uint16_t*)(ws + 64000000);        // 25,600,000 B
  float*    gc1 = (float*)(ws + 89600000);           // 25,600,000 B
  uint16_t* WT1 = (uint16_t*)(ws + 115200000);       //    262,144 B
  uint16_t* WT2 = (uint16_t*)(ws + 115462144);       //     65,536 B
  uint16_t* S2b = (uint16_t*)(ws + 115527680);       //  4,000,000 B
  float*    oacc = (float*)(ws + 119527680);         //  8,000,000 B  (total ~127.5 MB)

  hipMemsetAsync(gc1, 0, (size_t)N_NODES * 128 * 4, stream);

  k_cast_x<<<(3200000 + 255) / 256, 256, 0, stream>>>(x, xb, 3200000);
  k_prep_w1<<<(256 * 512) / 256, 256, 0, stream>>>(W1, Wr1, WT1);
  k_prep_w2<<<(128 * 256) / 256, 256, 0, stream>>>(W2, Wr2, WT2);

  dim3 g1(391, 2);
  k_gemm<512, 1><<<g1, 256, 0, stream>>>(xb, WT1, N_NODES, S1b, h, nullptr, br1, nullptr);

  k_spmm1<<<N_EDGES / 4, 256, 0, stream>>>(esrc, edst, eval, S1b, gc1);

  k_h<<<(N_NODES * 128 + 255) / 256, 256, 0, stream>>>(gc1, b1, h);

  dim3 g2(391, 1);
  k_gemm<256, 2><<<g2, 256, 0, stream>>>(h, WT2, N_NODES, S2b, nullptr, oacc, b2, br2);

  k_spmm2<<<N_EDGES / 4, 256, 0, stream>>>(esrc, edst, eval, S2b, oacc);

  k_lsm<<<(N_NODES + 3) / 4, 256, 0, stream>>>(oacc, out);
}

// Round 2
// 557.348 us; speedup vs baseline: 1.8682x; 1.8682x over previous
//
#include <hip/hip_runtime.h>
#include <stdint.h>

#define N_NODES 50000
#define N_EDGES 800000
#define NFEAT 512
#define NHID 128
#define NCLASS 40

typedef __attribute__((ext_vector_type(8))) __bf16 bf16x8;
typedef __attribute__((ext_vector_type(4))) float f32x4;

__device__ __forceinline__ uint16_t f2b(float f) {
  uint32_t x = __float_as_uint(f);
  uint32_t r = (x + 0x7fffu + ((x >> 16) & 1u)) >> 16;
  return (uint16_t)r;
}
__device__ __forceinline__ float b2f(uint16_t u) {
  return __uint_as_float(((uint32_t)u) << 16);
}

// ---------------- cast x (fp32 -> bf16), 8 elems/thread ----------------
__global__ void k_cast_x(const float* __restrict__ x, uint16_t* __restrict__ xb, int n8) {
  int i = blockIdx.x * blockDim.x + threadIdx.x;
  if (i >= n8) return;
  const float4* p = (const float4*)x + (size_t)i * 2;
  float4 a = p[0], b = p[1];
  union { uint16_t u[8]; uint4 v; } o;
  o.u[0] = f2b(a.x); o.u[1] = f2b(a.y); o.u[2] = f2b(a.z); o.u[3] = f2b(a.w);
  o.u[4] = f2b(b.x); o.u[5] = f2b(b.y); o.u[6] = f2b(b.z); o.u[7] = f2b(b.w);
  ((uint4*)xb)[i] = o.v;
}

// ---------------- weight prep: WT1[256][512] = [W1 | Wr1]^T bf16 ----------------
__global__ void k_prep_w1(const float* __restrict__ W1, const float* __restrict__ Wr1,
                          uint16_t* __restrict__ WT) {
  int idx = blockIdx.x * 256 + threadIdx.x;  // 256*512
  if (idx >= 256 * 512) return;
  int n = idx >> 9, k = idx & 511;
  float v = (n < 128) ? W1[(size_t)k * 128 + n] : Wr1[(size_t)k * 128 + (n - 128)];
  WT[idx] = f2b(v);
}

// ---------------- weight prep: WT2[128][256] = [W2 | Wr2 | 0pad]^T bf16 ----------------
__global__ void k_prep_w2(const float* __restrict__ W2, const float* __restrict__ Wr2,
                          uint16_t* __restrict__ WT) {
  int idx = blockIdx.x * 256 + threadIdx.x;  // 128*256
  if (idx >= 128 * 256) return;
  int n = idx >> 8, k = idx & 255;
  float v = 0.f;
  if (n < 40) v = W2[(size_t)k * 40 + n];
  else if (n < 80) v = Wr2[(size_t)k * 40 + (n - 40)];
  WT[idx] = f2b(v);
}

// ---------------- CSR build: histogram of dst ----------------
__global__ void k_hist(const int* __restrict__ dst, int* __restrict__ counts) {
  int e = blockIdx.x * 256 + threadIdx.x;
  if (e < N_EDGES) atomicAdd(&counts[dst[e]], 1);
}

// ---------------- CSR build: exclusive scan of counts -> offs[50001], single WG ----------------
__global__ void k_scan(const int* __restrict__ counts, int* __restrict__ offs) {
  __shared__ int part[1024];
  const int tid = threadIdx.x;
  const int PER = (N_NODES + 1023) / 1024;  // 49
  int base = tid * PER;
  int s = 0;
  for (int i = 0; i < PER; i++) {
    int idx = base + i;
    if (idx < N_NODES) s += counts[idx];
  }
  part[tid] = s;
  __syncthreads();
  for (int o = 1; o < 1024; o <<= 1) {
    int v = (tid >= o) ? part[tid - o] : 0;
    __syncthreads();
    part[tid] += v;
    __syncthreads();
  }
  int run = (tid == 0) ? 0 : part[tid - 1];
  for (int i = 0; i < PER; i++) {
    int idx = base + i;
    if (idx < N_NODES) {
      offs[idx] = run;
      run += counts[idx];
    }
  }
  if (tid == 1023) offs[N_NODES] = part[1023];
}

// ---------------- CSR build: scatter edges sorted by dst ----------------
__global__ void k_scatter(const int* __restrict__ src, const int* __restrict__ dst,
                          const float* __restrict__ val, const int* __restrict__ offs,
                          int* __restrict__ cursor, int2* __restrict__ es) {
  int e = blockIdx.x * 256 + threadIdx.x;
  if (e >= N_EDGES) return;
  int d = dst[e];
  int pos = offs[d] + atomicAdd(&cursor[d], 1);
  es[pos] = make_int2(src[e], __float_as_int(val[e]));
}

// ---------------- MFMA GEMM, m97 structure: 128x128 tile, 4 waves 2x2, BK=64 ----------------
template <int K, int EPI>
__global__ __launch_bounds__(256, 2) void k_gemm(
    const uint16_t* __restrict__ A, const uint16_t* __restrict__ BT, int M,
    uint16_t* __restrict__ out_bf_a, uint16_t* __restrict__ out_bf_b,
    float* __restrict__ out_f, const float* __restrict__ bias_a,
    const float* __restrict__ bias_b) {
  __shared__ uint16_t Al[128 * 64];
  __shared__ uint16_t Bl[128 * 64];
  const int tid = threadIdx.x;
  const int w = tid >> 6, lane = tid & 63;
  const int wm = w >> 1, wn = w & 1;
  const int m0 = blockIdx.x * 128;
  const int n0 = blockIdx.y * 128;

  f32x4 acc[4][4];
#pragma unroll
  for (int t = 0; t < 4; t++)
#pragma unroll
    for (int u = 0; u < 4; u++) acc[t][u] = (f32x4)0.f;

  const int lrow = lane >> 3;
  const int lcol = lane & 7;

  for (int kb = 0; kb < K / 64; ++kb) {
    __syncthreads();
    const int k0 = kb * 64;
#pragma unroll
    for (int i = 0; i < 4; i++) {
      int rr = (w * 4 + i) * 8 + lrow;
      int ra = m0 + rr;
      if (ra >= M) ra = M - 1;  // clamp tail rows (stores are guarded)
      const uint16_t* gA = A + (size_t)ra * K + k0 + lcol * 8;
      __builtin_amdgcn_global_load_lds(
          (const __attribute__((address_space(1))) void*)gA,
          (__attribute__((address_space(3))) void*)&Al[(w * 4 + i) * 512], 16, 0, 0);
      int rb = n0 + rr;
      const uint16_t* gB = BT + (size_t)rb * K + k0 + lcol * 8;
      __builtin_amdgcn_global_load_lds(
          (const __attribute__((address_space(1))) void*)gB,
          (__attribute__((address_space(3))) void*)&Bl[(w * 4 + i) * 512], 16, 0, 0);
    }
    __syncthreads();
#pragma unroll
    for (int s = 0; s < 2; s++) {
      bf16x8 av[4], bv[4];
#pragma unroll
      for (int t = 0; t < 4; t++)
        av[t] = *(const bf16x8*)&Al[(wm * 64 + t * 16 + (lane & 15)) * 64 + s * 32 + (lane >> 4) * 8];
#pragma unroll
      for (int u = 0; u < 4; u++)
        bv[u] = *(const bf16x8*)&Bl[(wn * 64 + u * 16 + (lane & 15)) * 64 + s * 32 + (lane >> 4) * 8];
#pragma unroll
      for (int t = 0; t < 4; t++)
#pragma unroll
        for (int u = 0; u < 4; u++)
          acc[t][u] = __builtin_amdgcn_mfma_f32_16x16x32_bf16(av[t], bv[u], acc[t][u], 0, 0, 0);
    }
  }

  const int cl = lane & 15, rq = lane >> 4;
#pragma unroll
  for (int t = 0; t < 4; t++) {
#pragma unroll
    for (int u = 0; u < 4; u++) {
#pragma unroll
      for (int r = 0; r < 4; r++) {
        int m = m0 + wm * 64 + t * 16 + rq * 4 + r;
        int n = n0 + wn * 64 + u * 16 + cl;
        if (m >= M) continue;
        float v = acc[t][u][r];
        if constexpr (EPI == 1) {
          if (n < 128)
            out_bf_a[(size_t)m * 128 + n] = f2b(v);  // S1 = x@W1
          else
            out_bf_b[(size_t)m * 256 + n] = f2b(v + bias_a[n - 128]);  // h right = x@Wr1+br1
        } else {
          if (n < 40)
            out_bf_a[(size_t)m * 40 + n] = f2b(v);  // S2 = h@W2
          else if (n < 80)
            out_f[(size_t)m * 40 + (n - 40)] = v + bias_a[n - 40] + bias_b[n - 40];  // h@Wr2+br2+b2
        }
      }
    }
  }
}

// ---------------- SpMM1 via CSR: wave/node, fused +b1, relu, bf16 pack -> h left ----------------
__global__ void k_spmm1_csr(const int* __restrict__ offs, const int2* __restrict__ es,
                            const uint16_t* __restrict__ S1b, const float* __restrict__ b1,
                            uint16_t* __restrict__ h) {
  int node = blockIdx.x * 4 + (threadIdx.x >> 6);
  if (node >= N_NODES) return;
  int lane = threadIdx.x & 63;
  int beg = offs[node], end = offs[node + 1];
  float a0 = 0.f, a1 = 0.f;
  for (int p = beg; p < end; p++) {
    int2 ev = es[p];  // wave-uniform 8B load
    float v = __int_as_float(ev.y);
    uint32_t pk = *(const uint32_t*)(S1b + (size_t)ev.x * 128 + lane * 2);
    a0 += v * b2f((uint16_t)(pk & 0xffffu));
    a1 += v * b2f((uint16_t)(pk >> 16));
  }
  a0 += b1[lane * 2];
  a1 += b1[lane * 2 + 1];
  a0 = a0 > 0.f ? a0 : 0.f;
  a1 = a1 > 0.f ? a1 : 0.f;
  *(uint32_t*)(h + (size_t)node * 256 + lane * 2) = (uint32_t)f2b(a0) | ((uint32_t)f2b(a1) << 16);
}

// ---------------- SpMM2 via CSR + log_softmax fused: wave/node ----------------
__global__ void k_spmm2_lsm(const int* __restrict__ offs, const int2* __restrict__ es,
                            const uint16_t* __restrict__ S2b, const float* __restrict__ oacc,
                            float* __restrict__ out) {
  int node = blockIdx.x * 4 + (threadIdx.x >> 6);
  if (node >= N_NODES) return;
  int lane = threadIdx.x & 63;
  int beg = offs[node], end = offs[node + 1];
  float a = 0.f;
  for (int p = beg; p < end; p++) {
    int2 ev = es[p];
    float v = __int_as_float(ev.y);
    if (lane < 40) a += v * b2f(S2b[(size_t)ev.x * 40 + lane]);
  }
  float val = (lane < 40) ? a + oacc[(size_t)node * 40 + lane] : -1e30f;
  float mv = val;
#pragma unroll
  for (int o = 32; o; o >>= 1) {
    float t = __shfl_xor(mv, o, 64);
    mv = mv > t ? mv : t;
  }
  float e = (lane < 40) ? __expf(val - mv) : 0.f;
  float se = e;
#pragma unroll
  for (int o = 32; o; o >>= 1) se += __shfl_xor(se, o, 64);
  if (lane < 40) out[(size_t)node * 40 + lane] = val - mv - __logf(se);
}

extern "C" void kernel_launch(void* const* d_in, const int* in_sizes, int n_in,
                              void* d_out, int out_size, void* d_ws, size_t ws_size,
                              hipStream_t stream) {
  const float* x = (const float*)d_in[0];
  const int* esrc = (const int*)d_in[1];
  const int* edst = (const int*)d_in[2];
  const float* eval = (const float*)d_in[3];
  const float* W1 = (const float*)d_in[4];
  const float* b1 = (const float*)d_in[5];
  const float* Wr1 = (const float*)d_in[6];
  const float* br1 = (const float*)d_in[7];
  const float* W2 = (const float*)d_in[8];
  const float* b2 = (const float*)d_in[9];
  const float* Wr2 = (const float*)d_in[10];
  const float* br2 = (const float*)d_in[11];
  float* out = (float*)d_out;

  char* ws = (char*)d_ws;
  uint16_t* xb   = (uint16_t*)(ws);              // 51,200,000
  uint16_t* S1b  = (uint16_t*)(ws + 51200000);   // 12,800,000
  uint16_t* h    = (uint16_t*)(ws + 64000000);   // 25,600,000
  uint16_t* WT1  = (uint16_t*)(ws + 89600000);   //    262,144
  uint16_t* WT2  = (uint16_t*)(ws + 89862144);   //     65,536
  uint16_t* S2b  = (uint16_t*)(ws + 89927680);   //  4,000,000
  float*    oacc = (float*)(ws + 93927680);      //  8,000,000
  int*      counts = (int*)(ws + 101927680);     //    200,000
  int*      cursor = (int*)(ws + 102127680);     //    200,000
  int*      offs   = (int*)(ws + 102327680);     //    200,004
  int2*     es     = (int2*)(ws + 102527744);    //  6,400,000  (total ~108.9 MB)

  hipMemsetAsync(counts, 0, N_NODES * 4, stream);
  hipMemsetAsync(cursor, 0, N_NODES * 4, stream);

  k_cast_x<<<(3200000 + 255) / 256, 256, 0, stream>>>(x, xb, 3200000);
  k_prep_w1<<<(256 * 512) / 256, 256, 0, stream>>>(W1, Wr1, WT1);
  k_prep_w2<<<(128 * 256) / 256, 256, 0, stream>>>(W2, Wr2, WT2);

  k_hist<<<(N_EDGES + 255) / 256, 256, 0, stream>>>(edst, counts);
  k_scan<<<1, 1024, 0, stream>>>(counts, offs);
  k_scatter<<<(N_EDGES + 255) / 256, 256, 0, stream>>>(esrc, edst, eval, offs, cursor, es);

  dim3 g1(391, 2);
  k_gemm<512, 1><<<g1, 256, 0, stream>>>(xb, WT1, N_NODES, S1b, h, nullptr, br1, nullptr);

  k_spmm1_csr<<<(N_NODES + 3) / 4, 256, 0, stream>>>(offs, es, S1b, b1, h);

  dim3 g2(391, 1);
  k_gemm<256, 2><<<g2, 256, 0, stream>>>(h, WT2, N_NODES, S2b, nullptr, oacc, b2, br2);

  k_spmm2_lsm<<<(N_NODES + 3) / 4, 256, 0, stream>>>(offs, es, S2b, oacc, out);
}

// Round 3
// 393.169 us; speedup vs baseline: 2.6483x; 1.4176x over previous
//
#include <hip/hip_runtime.h>
#include <stdint.h>

#define N_NODES 50000
#define N_EDGES 800000
#define NFEAT 512
#define NHID 128
#define NCLASS 40
#define NB 196  // ceil(50000/256)

typedef __attribute__((ext_vector_type(8))) __bf16 bf16x8;
typedef __attribute__((ext_vector_type(4))) float f32x4;

__device__ __forceinline__ uint16_t f2b(float f) {
  uint32_t x = __float_as_uint(f);
  uint32_t r = (x + 0x7fffu + ((x >> 16) & 1u)) >> 16;
  return (uint16_t)r;
}
__device__ __forceinline__ float b2f(uint16_t u) {
  return __uint_as_float(((uint32_t)u) << 16);
}

// ---------------- cast x (fp32 -> bf16), 8 elems/thread ----------------
__global__ void k_cast_x(const float* __restrict__ x, uint16_t* __restrict__ xb, int n8) {
  int i = blockIdx.x * blockDim.x + threadIdx.x;
  if (i >= n8) return;
  const float4* p = (const float4*)x + (size_t)i * 2;
  float4 a = p[0], b = p[1];
  union { uint16_t u[8]; uint4 v; } o;
  o.u[0] = f2b(a.x); o.u[1] = f2b(a.y); o.u[2] = f2b(a.z); o.u[3] = f2b(a.w);
  o.u[4] = f2b(b.x); o.u[5] = f2b(b.y); o.u[6] = f2b(b.z); o.u[7] = f2b(b.w);
  ((uint4*)xb)[i] = o.v;
}

// ---------------- weight prep ----------------
__global__ void k_prep_w1(const float* __restrict__ W1, const float* __restrict__ Wr1,
                          uint16_t* __restrict__ WT) {
  int idx = blockIdx.x * 256 + threadIdx.x;  // 256*512
  if (idx >= 256 * 512) return;
  int n = idx >> 9, k = idx & 511;
  float v = (n < 128) ? W1[(size_t)k * 128 + n] : Wr1[(size_t)k * 128 + (n - 128)];
  WT[idx] = f2b(v);
}

__global__ void k_prep_w2(const float* __restrict__ W2, const float* __restrict__ Wr2,
                          uint16_t* __restrict__ WT) {
  int idx = blockIdx.x * 256 + threadIdx.x;  // 128*256
  if (idx >= 128 * 256) return;
  int n = idx >> 8, k = idx & 255;
  float v = 0.f;
  if (n < 40) v = W2[(size_t)k * 40 + n];
  else if (n < 80) v = Wr2[(size_t)k * 40 + (n - 40)];
  WT[idx] = f2b(v);
}

// ---------------- CSR build ----------------
__global__ void k_hist(const int* __restrict__ dst, int* __restrict__ counts) {
  int e = blockIdx.x * 256 + threadIdx.x;
  if (e < N_EDGES) atomicAdd(&counts[dst[e]], 1);
}

// per-block reduce of 256 counts -> blocksums[b]
__global__ void k_blocksum(const int* __restrict__ counts, int* __restrict__ blocksums) {
  __shared__ int red[256];
  int t = threadIdx.x, idx = blockIdx.x * 256 + t;
  red[t] = (idx < N_NODES) ? counts[idx] : 0;
  __syncthreads();
  for (int o = 128; o; o >>= 1) {
    if (t < o) red[t] += red[t + o];
    __syncthreads();
  }
  if (t == 0) blocksums[blockIdx.x] = red[0];
}

// per-block: prefix = sum(blocksums[<b]); local 256-wide exclusive scan; write offs
__global__ void k_scan2(const int* __restrict__ counts, const int* __restrict__ blocksums,
                        int* __restrict__ offs) {
  __shared__ int red[256];
  __shared__ int sc[256];
  int b = blockIdx.x, t = threadIdx.x;
  red[t] = (t < b && t < NB) ? blocksums[t] : 0;
  __syncthreads();
  for (int o = 128; o; o >>= 1) {
    if (t < o) red[t] += red[t + o];
    __syncthreads();
  }
  int prefix = red[0];
  int idx = b * 256 + t;
  int c = (idx < N_NODES) ? counts[idx] : 0;
  sc[t] = c;
  __syncthreads();
  for (int o = 1; o < 256; o <<= 1) {
    int v = (t >= o) ? sc[t - o] : 0;
    __syncthreads();
    sc[t] += v;
    __syncthreads();
  }
  if (idx <= N_NODES) offs[idx] = prefix + sc[t] - c;
}

__global__ void k_scatter(const int* __restrict__ src, const int* __restrict__ dst,
                          const float* __restrict__ val, const int* __restrict__ offs,
                          int* __restrict__ cursor, int2* __restrict__ es) {
  int e = blockIdx.x * 256 + threadIdx.x;
  if (e >= N_EDGES) return;
  int d = dst[e];
  int pos = offs[d] + atomicAdd(&cursor[d], 1);
  es[pos] = make_int2(src[e], __float_as_int(val[e]));
}

// ---------------- MFMA GEMM, m97 structure ----------------
template <int K, int EPI>
__global__ __launch_bounds__(256, 2) void k_gemm(
    const uint16_t* __restrict__ A, const uint16_t* __restrict__ BT, int M,
    uint16_t* __restrict__ out_bf_a, uint16_t* __restrict__ out_bf_b,
    float* __restrict__ out_f, const float* __restrict__ bias_a,
    const float* __restrict__ bias_b) {
  __shared__ uint16_t Al[128 * 64];
  __shared__ uint16_t Bl[128 * 64];
  const int tid = threadIdx.x;
  const int w = tid >> 6, lane = tid & 63;
  const int wm = w >> 1, wn = w & 1;
  const int m0 = blockIdx.x * 128;
  const int n0 = blockIdx.y * 128;

  f32x4 acc[4][4];
#pragma unroll
  for (int t = 0; t < 4; t++)
#pragma unroll
    for (int u = 0; u < 4; u++) acc[t][u] = (f32x4)0.f;

  const int lrow = lane >> 3;
  const int lcol = lane & 7;

  for (int kb = 0; kb < K / 64; ++kb) {
    __syncthreads();
    const int k0 = kb * 64;
#pragma unroll
    for (int i = 0; i < 4; i++) {
      int rr = (w * 4 + i) * 8 + lrow;
      int ra = m0 + rr;
      if (ra >= M) ra = M - 1;
      const uint16_t* gA = A + (size_t)ra * K + k0 + lcol * 8;
      __builtin_amdgcn_global_load_lds(
          (const __attribute__((address_space(1))) void*)gA,
          (__attribute__((address_space(3))) void*)&Al[(w * 4 + i) * 512], 16, 0, 0);
      int rb = n0 + rr;
      const uint16_t* gB = BT + (size_t)rb * K + k0 + lcol * 8;
      __builtin_amdgcn_global_load_lds(
          (const __attribute__((address_space(1))) void*)gB,
          (__attribute__((address_space(3))) void*)&Bl[(w * 4 + i) * 512], 16, 0, 0);
    }
    __syncthreads();
#pragma unroll
    for (int s = 0; s < 2; s++) {
      bf16x8 av[4], bv[4];
#pragma unroll
      for (int t = 0; t < 4; t++)
        av[t] = *(const bf16x8*)&Al[(wm * 64 + t * 16 + (lane & 15)) * 64 + s * 32 + (lane >> 4) * 8];
#pragma unroll
      for (int u = 0; u < 4; u++)
        bv[u] = *(const bf16x8*)&Bl[(wn * 64 + u * 16 + (lane & 15)) * 64 + s * 32 + (lane >> 4) * 8];
#pragma unroll
      for (int t = 0; t < 4; t++)
#pragma unroll
        for (int u = 0; u < 4; u++)
          acc[t][u] = __builtin_amdgcn_mfma_f32_16x16x32_bf16(av[t], bv[u], acc[t][u], 0, 0, 0);
    }
  }

  const int cl = lane & 15, rq = lane >> 4;
#pragma unroll
  for (int t = 0; t < 4; t++) {
#pragma unroll
    for (int u = 0; u < 4; u++) {
#pragma unroll
      for (int r = 0; r < 4; r++) {
        int m = m0 + wm * 64 + t * 16 + rq * 4 + r;
        int n = n0 + wn * 64 + u * 16 + cl;
        if (m >= M) continue;
        float v = acc[t][u][r];
        if constexpr (EPI == 1) {
          if (n < 128)
            out_bf_a[(size_t)m * 128 + n] = f2b(v);
          else
            out_bf_b[(size_t)m * 256 + n] = f2b(v + bias_a[n - 128]);
        } else {
          if (n < 40)
            out_bf_a[(size_t)m * 40 + n] = f2b(v);
          else if (n < 80)
            out_f[(size_t)m * 40 + (n - 40)] = v + bias_a[n - 40] + bias_b[n - 40];
        }
      }
    }
  }
}

// ---------------- SpMM1 via CSR: wave/node, 4-way MLP unroll, fused b1+relu+pack ----------------
__global__ void k_spmm1_csr(const int* __restrict__ offs, const int2* __restrict__ es,
                            const uint16_t* __restrict__ S1b, const float* __restrict__ b1,
                            uint16_t* __restrict__ h) {
  int node = blockIdx.x * 4 + (threadIdx.x >> 6);
  if (node >= N_NODES) return;
  int lane = threadIdx.x & 63;
  int beg = offs[node], end = offs[node + 1];
  float a0 = 0.f, a1 = 0.f;
  int p = beg;
  for (; p + 4 <= end; p += 4) {
    int2 e0 = es[p], e1 = es[p + 1], e2 = es[p + 2], e3 = es[p + 3];
    uint32_t p0 = *(const uint32_t*)(S1b + (size_t)e0.x * 128 + lane * 2);
    uint32_t p1 = *(const uint32_t*)(S1b + (size_t)e1.x * 128 + lane * 2);
    uint32_t p2 = *(const uint32_t*)(S1b + (size_t)e2.x * 128 + lane * 2);
    uint32_t p3 = *(const uint32_t*)(S1b + (size_t)e3.x * 128 + lane * 2);
    float v0 = __int_as_float(e0.y), v1 = __int_as_float(e1.y);
    float v2 = __int_as_float(e2.y), v3 = __int_as_float(e3.y);
    a0 += v0 * b2f((uint16_t)p0) + v1 * b2f((uint16_t)p1) + v2 * b2f((uint16_t)p2) + v3 * b2f((uint16_t)p3);
    a1 += v0 * b2f((uint16_t)(p0 >> 16)) + v1 * b2f((uint16_t)(p1 >> 16)) +
          v2 * b2f((uint16_t)(p2 >> 16)) + v3 * b2f((uint16_t)(p3 >> 16));
  }
  for (; p < end; p++) {
    int2 ev = es[p];
    float v = __int_as_float(ev.y);
    uint32_t pk = *(const uint32_t*)(S1b + (size_t)ev.x * 128 + lane * 2);
    a0 += v * b2f((uint16_t)pk);
    a1 += v * b2f((uint16_t)(pk >> 16));
  }
  a0 += b1[lane * 2];
  a1 += b1[lane * 2 + 1];
  a0 = a0 > 0.f ? a0 : 0.f;
  a1 = a1 > 0.f ? a1 : 0.f;
  *(uint32_t*)(h + (size_t)node * 256 + lane * 2) = (uint32_t)f2b(a0) | ((uint32_t)f2b(a1) << 16);
}

// ---------------- SpMM2 via CSR + log_softmax fused: wave/node, 4-way unroll ----------------
__global__ void k_spmm2_lsm(const int* __restrict__ offs, const int2* __restrict__ es,
                            const uint16_t* __restrict__ S2b, const float* __restrict__ oacc,
                            float* __restrict__ out) {
  int node = blockIdx.x * 4 + (threadIdx.x >> 6);
  if (node >= N_NODES) return;
  int lane = threadIdx.x & 63;
  int beg = offs[node], end = offs[node + 1];
  float a = 0.f;
  int fl = lane < 40 ? lane : 0;
  int p = beg;
  for (; p + 4 <= end; p += 4) {
    int2 e0 = es[p], e1 = es[p + 1], e2 = es[p + 2], e3 = es[p + 3];
    float x0 = b2f(S2b[(size_t)e0.x * 40 + fl]);
    float x1 = b2f(S2b[(size_t)e1.x * 40 + fl]);
    float x2 = b2f(S2b[(size_t)e2.x * 40 + fl]);
    float x3 = b2f(S2b[(size_t)e3.x * 40 + fl]);
    a += __int_as_float(e0.y) * x0 + __int_as_float(e1.y) * x1 +
         __int_as_float(e2.y) * x2 + __int_as_float(e3.y) * x3;
  }
  for (; p < end; p++) {
    int2 ev = es[p];
    a += __int_as_float(ev.y) * b2f(S2b[(size_t)ev.x * 40 + fl]);
  }
  float val = (lane < 40) ? a + oacc[(size_t)node * 40 + lane] : -1e30f;
  float mv = val;
#pragma unroll
  for (int o = 32; o; o >>= 1) {
    float t = __shfl_xor(mv, o, 64);
    mv = mv > t ? mv : t;
  }
  float e = (lane < 40) ? __expf(val - mv) : 0.f;
  float se = e;
#pragma unroll
  for (int o = 32; o; o >>= 1) se += __shfl_xor(se, o, 64);
  if (lane < 40) out[(size_t)node * 40 + lane] = val - mv - __logf(se);
}

extern "C" void kernel_launch(void* const* d_in, const int* in_sizes, int n_in,
                              void* d_out, int out_size, void* d_ws, size_t ws_size,
                              hipStream_t stream) {
  const float* x = (const float*)d_in[0];
  const int* esrc = (const int*)d_in[1];
  const int* edst = (const int*)d_in[2];
  const float* eval = (const float*)d_in[3];
  const float* W1 = (const float*)d_in[4];
  const float* b1 = (const float*)d_in[5];
  const float* Wr1 = (const float*)d_in[6];
  const float* br1 = (const float*)d_in[7];
  const float* W2 = (const float*)d_in[8];
  const float* b2 = (const float*)d_in[9];
  const float* Wr2 = (const float*)d_in[10];
  const float* br2 = (const float*)d_in[11];
  float* out = (float*)d_out;

  char* ws = (char*)d_ws;
  uint16_t* xb   = (uint16_t*)(ws);              // 51,200,000
  uint16_t* S1b  = (uint16_t*)(ws + 51200000);   // 12,800,000
  uint16_t* h    = (uint16_t*)(ws + 64000000);   // 25,600,000
  uint16_t* WT1  = (uint16_t*)(ws + 89600000);   //    262,144
  uint16_t* WT2  = (uint16_t*)(ws + 89862144);   //     65,536
  uint16_t* S2b  = (uint16_t*)(ws + 89927680);   //  4,000,000
  float*    oacc = (float*)(ws + 93927680);      //  8,000,000
  int*      counts = (int*)(ws + 101927680);     //    200,000
  int*      cursor = (int*)(ws + 102127680);     //    200,000
  int*      offs   = (int*)(ws + 102327680);     //    200,004
  int2*     es     = (int2*)(ws + 102527744);    //  6,400,000
  int*      blocksums = (int*)(ws + 108927744);  //        784  (total ~108.93 MB)

  hipMemsetAsync(counts, 0, 400000, stream);  // counts + cursor (adjacent)

  k_cast_x<<<(3200000 + 255) / 256, 256, 0, stream>>>(x, xb, 3200000);
  k_prep_w1<<<(256 * 512) / 256, 256, 0, stream>>>(W1, Wr1, WT1);
  k_prep_w2<<<(128 * 256) / 256, 256, 0, stream>>>(W2, Wr2, WT2);

  k_hist<<<(N_EDGES + 255) / 256, 256, 0, stream>>>(edst, counts);
  k_blocksum<<<NB, 256, 0, stream>>>(counts, blocksums);
  k_scan2<<<NB, 256, 0, stream>>>(counts, blocksums, offs);
  k_scatter<<<(N_EDGES + 255) / 256, 256, 0, stream>>>(esrc, edst, eval, offs, cursor, es);

  dim3 g1(391, 2);
  k_gemm<512, 1><<<g1, 256, 0, stream>>>(xb, WT1, N_NODES, S1b, h, nullptr, br1, nullptr);

  k_spmm1_csr<<<(N_NODES + 3) / 4, 256, 0, stream>>>(offs, es, S1b, b1, h);

  dim3 g2(391, 1);
  k_gemm<256, 2><<<g2, 256, 0, stream>>>(h, WT2, N_NODES, S2b, nullptr, oacc, b2, br2);

  k_spmm2_lsm<<<(N_NODES + 3) / 4, 256, 0, stream>>>(offs, es, S2b, oacc, out);
}

// Round 4
// 364.681 us; speedup vs baseline: 2.8551x; 1.0781x over previous
//
#include <hip/hip_runtime.h>
#include <stdint.h>

#define N_NODES 50000
#define N_EDGES 800000
#define NFEAT 512
#define NHID 128
#define NCLASS 40
#define NB 196  // ceil(50000/256)

typedef __attribute__((ext_vector_type(8))) __bf16 bf16x8;
typedef __attribute__((ext_vector_type(4))) float f32x4;

__device__ __forceinline__ uint16_t f2b(float f) {
  uint32_t x = __float_as_uint(f);
  uint32_t r = (x + 0x7fffu + ((x >> 16) & 1u)) >> 16;
  return (uint16_t)r;
}
__device__ __forceinline__ float b2f(uint16_t u) {
  return __uint_as_float(((uint32_t)u) << 16);
}

// ---------------- weight prep ----------------
__global__ void k_prep_w1(const float* __restrict__ W1, const float* __restrict__ Wr1,
                          uint16_t* __restrict__ WT) {
  int idx = blockIdx.x * 256 + threadIdx.x;  // 256*512
  if (idx >= 256 * 512) return;
  int n = idx >> 9, k = idx & 511;
  float v = (n < 128) ? W1[(size_t)k * 128 + n] : Wr1[(size_t)k * 128 + (n - 128)];
  WT[idx] = f2b(v);
}

__global__ void k_prep_w2(const float* __restrict__ W2, const float* __restrict__ Wr2,
                          uint16_t* __restrict__ WT) {
  int idx = blockIdx.x * 256 + threadIdx.x;  // 128*256
  if (idx >= 128 * 256) return;
  int n = idx >> 8, k = idx & 255;
  float v = 0.f;
  if (n < 40) v = W2[(size_t)k * 40 + n];
  else if (n < 80) v = Wr2[(size_t)k * 40 + (n - 40)];
  WT[idx] = f2b(v);
}

// ---------------- CSR build ----------------
__global__ void k_hist(const int* __restrict__ dst, int* __restrict__ counts) {
  int e = blockIdx.x * 256 + threadIdx.x;
  if (e < N_EDGES) atomicAdd(&counts[dst[e]], 1);
}

__global__ void k_blocksum(const int* __restrict__ counts, int* __restrict__ blocksums) {
  __shared__ int red[256];
  int t = threadIdx.x, idx = blockIdx.x * 256 + t;
  red[t] = (idx < N_NODES) ? counts[idx] : 0;
  __syncthreads();
  for (int o = 128; o; o >>= 1) {
    if (t < o) red[t] += red[t + o];
    __syncthreads();
  }
  if (t == 0) blocksums[blockIdx.x] = red[0];
}

__global__ void k_scan2(const int* __restrict__ counts, const int* __restrict__ blocksums,
                        int* __restrict__ offs) {
  __shared__ int red[256];
  __shared__ int sc[256];
  int b = blockIdx.x, t = threadIdx.x;
  red[t] = (t < b && t < NB) ? blocksums[t] : 0;
  __syncthreads();
  for (int o = 128; o; o >>= 1) {
    if (t < o) red[t] += red[t + o];
    __syncthreads();
  }
  int prefix = red[0];
  int idx = b * 256 + t;
  int c = (idx < N_NODES) ? counts[idx] : 0;
  sc[t] = c;
  __syncthreads();
  for (int o = 1; o < 256; o <<= 1) {
    int v = (t >= o) ? sc[t - o] : 0;
    __syncthreads();
    sc[t] += v;
    __syncthreads();
  }
  if (idx <= N_NODES) offs[idx] = prefix + sc[t] - c;
}

__global__ void k_scatter(const int* __restrict__ src, const int* __restrict__ dst,
                          const float* __restrict__ val, const int* __restrict__ offs,
                          int* __restrict__ cursor, int2* __restrict__ es) {
  int e = blockIdx.x * 256 + threadIdx.x;
  if (e >= N_EDGES) return;
  int d = dst[e];
  int pos = offs[d] + atomicAdd(&cursor[d], 1);
  es[pos] = make_int2(src[e], __float_as_int(val[e]));
}

// ---------------- fused cast+GEMM1: x(fp32) @ WT1^T, 128x256 tile, 8 waves 2x4 ----------------
// Al padded to stride 72 elems to break 16-way ds_write bank conflicts in A staging.
__global__ __launch_bounds__(512) void k_gemm1_fused(
    const float* __restrict__ x, const uint16_t* __restrict__ BT,
    uint16_t* __restrict__ S1b, uint16_t* __restrict__ h, const float* __restrict__ br1) {
  __shared__ uint16_t Al[128 * 72];  // 18 KB
  __shared__ uint16_t Bl[256 * 64];  // 32 KB
  const int tid = threadIdx.x;
  const int w = tid >> 6, lane = tid & 63;
  const int wm = w >> 2, wn = w & 3;
  const int m0 = blockIdx.x * 128;
  const int M = N_NODES;

  f32x4 acc[4][4];
#pragma unroll
  for (int t = 0; t < 4; t++)
#pragma unroll
    for (int u = 0; u < 4; u++) acc[t][u] = (f32x4)0.f;

  const int arow = tid >> 2;       // 0..127
  const int aslot = tid & 3;       // 0..3 (16 floats each)
  int ar = m0 + arow;
  if (ar >= M) ar = M - 1;
  const float* gxbase = x + (size_t)ar * NFEAT + aslot * 16;

  for (int kb = 0; kb < 8; ++kb) {
    __syncthreads();
    const int k0 = kb * 64;
    // A: fp32 -> bf16 -> LDS (stride 72)
    {
      const float4* gp = (const float4*)(gxbase + k0);
      float4 f0 = gp[0], f1 = gp[1], f2 = gp[2], f3 = gp[3];
      union { uint16_t u[8]; uint4 v; } o0, o1;
      o0.u[0] = f2b(f0.x); o0.u[1] = f2b(f0.y); o0.u[2] = f2b(f0.z); o0.u[3] = f2b(f0.w);
      o0.u[4] = f2b(f1.x); o0.u[5] = f2b(f1.y); o0.u[6] = f2b(f1.z); o0.u[7] = f2b(f1.w);
      o1.u[0] = f2b(f2.x); o1.u[1] = f2b(f2.y); o1.u[2] = f2b(f2.z); o1.u[3] = f2b(f2.w);
      o1.u[4] = f2b(f3.x); o1.u[5] = f2b(f3.y); o1.u[6] = f2b(f3.z); o1.u[7] = f2b(f3.w);
      *(uint4*)&Al[arow * 72 + aslot * 16] = o0.v;
      *(uint4*)&Al[arow * 72 + aslot * 16 + 8] = o1.v;
    }
    // B: 256x64 bf16 via global_load_lds, 8 waves x 4 issues x 1KB
#pragma unroll
    for (int i = 0; i < 4; i++) {
      int chunk = w * 4 + i;  // 0..31, 8 rows each
      const uint16_t* gB = BT + (size_t)(chunk * 8 + (lane >> 3)) * NFEAT + k0 + (lane & 7) * 8;
      __builtin_amdgcn_global_load_lds(
          (const __attribute__((address_space(1))) void*)gB,
          (__attribute__((address_space(3))) void*)&Bl[chunk * 512], 16, 0, 0);
    }
    __syncthreads();
#pragma unroll
    for (int s = 0; s < 2; s++) {
      bf16x8 av[4], bv[4];
#pragma unroll
      for (int t = 0; t < 4; t++)
        av[t] = *(const bf16x8*)&Al[(wm * 64 + t * 16 + (lane & 15)) * 72 + s * 32 + (lane >> 4) * 8];
#pragma unroll
      for (int u = 0; u < 4; u++)
        bv[u] = *(const bf16x8*)&Bl[(wn * 64 + u * 16 + (lane & 15)) * 64 + s * 32 + (lane >> 4) * 8];
#pragma unroll
      for (int t = 0; t < 4; t++)
#pragma unroll
        for (int u = 0; u < 4; u++)
          acc[t][u] = __builtin_amdgcn_mfma_f32_16x16x32_bf16(av[t], bv[u], acc[t][u], 0, 0, 0);
    }
  }

  const int cl = lane & 15, rq = lane >> 4;
#pragma unroll
  for (int t = 0; t < 4; t++) {
#pragma unroll
    for (int u = 0; u < 4; u++) {
#pragma unroll
      for (int r = 0; r < 4; r++) {
        int m = m0 + wm * 64 + t * 16 + rq * 4 + r;
        int n = wn * 64 + u * 16 + cl;  // 0..255
        if (m >= M) continue;
        float v = acc[t][u][r];
        if (n < 128)
          S1b[(size_t)m * 128 + n] = f2b(v);  // x@W1 (b1 added post-spmm)
        else
          h[(size_t)m * 256 + n] = f2b(v + br1[n - 128]);  // h right = x@Wr1+br1
      }
    }
  }
}

// ---------------- GEMM2: h(bf16) @ WT2^T, 128x128 tile, padded epilogue ----------------
__global__ __launch_bounds__(256, 2) void k_gemm2(
    const uint16_t* __restrict__ A, const uint16_t* __restrict__ BT, int M,
    uint16_t* __restrict__ S2b, float* __restrict__ oacc,
    const float* __restrict__ b2, const float* __restrict__ br2) {
  __shared__ uint16_t Al[128 * 64];
  __shared__ uint16_t Bl[128 * 64];
  const int tid = threadIdx.x;
  const int w = tid >> 6, lane = tid & 63;
  const int wm = w >> 1, wn = w & 1;
  const int m0 = blockIdx.x * 128;
  const int K = 256;

  f32x4 acc[4][4];
#pragma unroll
  for (int t = 0; t < 4; t++)
#pragma unroll
    for (int u = 0; u < 4; u++) acc[t][u] = (f32x4)0.f;

  const int lrow = lane >> 3;
  const int lcol = lane & 7;

  for (int kb = 0; kb < K / 64; ++kb) {
    __syncthreads();
    const int k0 = kb * 64;
#pragma unroll
    for (int i = 0; i < 4; i++) {
      int rr = (w * 4 + i) * 8 + lrow;
      int ra = m0 + rr;
      if (ra >= M) ra = M - 1;
      const uint16_t* gA = A + (size_t)ra * K + k0 + lcol * 8;
      __builtin_amdgcn_global_load_lds(
          (const __attribute__((address_space(1))) void*)gA,
          (__attribute__((address_space(3))) void*)&Al[(w * 4 + i) * 512], 16, 0, 0);
      const uint16_t* gB = BT + (size_t)rr * K + k0 + lcol * 8;
      __builtin_amdgcn_global_load_lds(
          (const __attribute__((address_space(1))) void*)gB,
          (__attribute__((address_space(3))) void*)&Bl[(w * 4 + i) * 512], 16, 0, 0);
    }
    __syncthreads();
#pragma unroll
    for (int s = 0; s < 2; s++) {
      bf16x8 av[4], bv[4];
#pragma unroll
      for (int t = 0; t < 4; t++)
        av[t] = *(const bf16x8*)&Al[(wm * 64 + t * 16 + (lane & 15)) * 64 + s * 32 + (lane >> 4) * 8];
#pragma unroll
      for (int u = 0; u < 4; u++)
        bv[u] = *(const bf16x8*)&Bl[(wn * 64 + u * 16 + (lane & 15)) * 64 + s * 32 + (lane >> 4) * 8];
#pragma unroll
      for (int t = 0; t < 4; t++)
#pragma unroll
        for (int u = 0; u < 4; u++)
          acc[t][u] = __builtin_amdgcn_mfma_f32_16x16x32_bf16(av[t], bv[u], acc[t][u], 0, 0, 0);
    }
  }

  const int cl = lane & 15, rq = lane >> 4;
#pragma unroll
  for (int t = 0; t < 4; t++) {
#pragma unroll
    for (int u = 0; u < 4; u++) {
#pragma unroll
      for (int r = 0; r < 4; r++) {
        int m = m0 + wm * 64 + t * 16 + rq * 4 + r;
        int n = wn * 64 + u * 16 + cl;
        if (m >= M) continue;
        float v = acc[t][u][r];
        // S2b padded to 64 cols; oacc padded to 64 cols
        if (n < 40) S2b[(size_t)m * 64 + n] = f2b(v);
        else if (n < 64) S2b[(size_t)m * 64 + n] = 0;
        if (n >= 40 && n < 80) oacc[(size_t)m * 64 + (n - 40)] = v + b2[n - 40] + br2[n - 40];
        else if (n >= 80 && n < 104) oacc[(size_t)m * 64 + (n - 40)] = 0.f;
      }
    }
  }
}

// ---------------- SpMM1 via CSR: wave/node, 4 edges/iter, dwordx4 gathers ----------------
__global__ void k_spmm1_csr(const int* __restrict__ offs, const int2* __restrict__ es,
                            const uint16_t* __restrict__ S1b, const float* __restrict__ b1,
                            uint16_t* __restrict__ h) {
  int node = blockIdx.x * 4 + (threadIdx.x >> 6);
  if (node >= N_NODES) return;
  int lane = threadIdx.x & 63;
  int eg = lane >> 4;  // 0..3 edge slot
  int fg = lane & 15;  // 0..15 feat group (8 feats)
  int beg = offs[node], end = offs[node + 1];
  float a[8];
#pragma unroll
  for (int j = 0; j < 8; j++) a[j] = 0.f;
  for (int p = beg; p < end; p += 4) {
    int pe = p + eg;
    bool ok = pe < end;
    int2 ev = es[ok ? pe : beg];
    float v = ok ? __int_as_float(ev.y) : 0.f;
    uint4 g = *(const uint4*)(S1b + (size_t)ev.x * 128 + fg * 8);
    a[0] += v * b2f((uint16_t)g.x); a[1] += v * b2f((uint16_t)(g.x >> 16));
    a[2] += v * b2f((uint16_t)g.y); a[3] += v * b2f((uint16_t)(g.y >> 16));
    a[4] += v * b2f((uint16_t)g.z); a[5] += v * b2f((uint16_t)(g.z >> 16));
    a[6] += v * b2f((uint16_t)g.w); a[7] += v * b2f((uint16_t)(g.w >> 16));
  }
#pragma unroll
  for (int j = 0; j < 8; j++) {
    a[j] += __shfl_xor(a[j], 16, 64);
    a[j] += __shfl_xor(a[j], 32, 64);
  }
  if (eg == 0) {
    const float4* bp = (const float4*)(b1 + fg * 8);
    float4 ba = bp[0], bb = bp[1];
    float r0 = a[0] + ba.x, r1 = a[1] + ba.y, r2 = a[2] + ba.z, r3 = a[3] + ba.w;
    float r4 = a[4] + bb.x, r5 = a[5] + bb.y, r6 = a[6] + bb.z, r7 = a[7] + bb.w;
    union { uint16_t u[8]; uint4 v; } o;
    o.u[0] = f2b(r0 > 0.f ? r0 : 0.f); o.u[1] = f2b(r1 > 0.f ? r1 : 0.f);
    o.u[2] = f2b(r2 > 0.f ? r2 : 0.f); o.u[3] = f2b(r3 > 0.f ? r3 : 0.f);
    o.u[4] = f2b(r4 > 0.f ? r4 : 0.f); o.u[5] = f2b(r5 > 0.f ? r5 : 0.f);
    o.u[6] = f2b(r6 > 0.f ? r6 : 0.f); o.u[7] = f2b(r7 > 0.f ? r7 : 0.f);
    *(uint4*)(h + (size_t)node * 256 + fg * 8) = o.v;
  }
}

// ---------------- SpMM2 via CSR + log_softmax: wave/node, 8 edges/iter (64-padded rows) ----------------
__global__ void k_spmm2_lsm(const int* __restrict__ offs, const int2* __restrict__ es,
                            const uint16_t* __restrict__ S2b, const float* __restrict__ oacc,
                            float* __restrict__ out) {
  int node = blockIdx.x * 4 + (threadIdx.x >> 6);
  if (node >= N_NODES) return;
  int lane = threadIdx.x & 63;
  int eg = lane >> 3;  // 0..7 edge slot
  int fg = lane & 7;   // 0..7 feat group (8 feats of 64-padded row)
  int beg = offs[node], end = offs[node + 1];
  float a[8];
#pragma unroll
  for (int j = 0; j < 8; j++) a[j] = 0.f;
  for (int p = beg; p < end; p += 8) {
    int pe = p + eg;
    bool ok = pe < end;
    int2 ev = es[ok ? pe : beg];
    float v = ok ? __int_as_float(ev.y) : 0.f;
    uint4 g = *(const uint4*)(S2b + (size_t)ev.x * 64 + fg * 8);
    a[0] += v * b2f((uint16_t)g.x); a[1] += v * b2f((uint16_t)(g.x >> 16));
    a[2] += v * b2f((uint16_t)g.y); a[3] += v * b2f((uint16_t)(g.y >> 16));
    a[4] += v * b2f((uint16_t)g.z); a[5] += v * b2f((uint16_t)(g.z >> 16));
    a[6] += v * b2f((uint16_t)g.w); a[7] += v * b2f((uint16_t)(g.w >> 16));
  }
#pragma unroll
  for (int j = 0; j < 8; j++) {
    a[j] += __shfl_xor(a[j], 8, 64);
    a[j] += __shfl_xor(a[j], 16, 64);
    a[j] += __shfl_xor(a[j], 32, 64);
  }
  const float4* op = (const float4*)(oacc + (size_t)node * 64 + fg * 8);
  float4 o0 = op[0], o1 = op[1];
  float v0 = a[0] + o0.x, v1 = a[1] + o0.y, v2 = a[2] + o0.z, v3 = a[3] + o0.w;
  float v4 = a[4] + o1.x, v5 = a[5] + o1.y, v6 = a[6] + o1.z, v7 = a[7] + o1.w;
  bool valid = fg < 5;  // feats 0..39
  float m01 = v0 > v1 ? v0 : v1, m23 = v2 > v3 ? v2 : v3;
  float m45 = v4 > v5 ? v4 : v5, m67 = v6 > v7 ? v6 : v7;
  float ml = m01 > m23 ? m01 : m23;
  float mh = m45 > m67 ? m45 : m67;
  float mv = ml > mh ? ml : mh;
  mv = valid ? mv : -1e30f;
#pragma unroll
  for (int o = 1; o <= 4; o <<= 1) {
    float t = __shfl_xor(mv, o, 64);
    mv = mv > t ? mv : t;
  }
  float se = 0.f;
  if (valid)
    se = __expf(v0 - mv) + __expf(v1 - mv) + __expf(v2 - mv) + __expf(v3 - mv) +
         __expf(v4 - mv) + __expf(v5 - mv) + __expf(v6 - mv) + __expf(v7 - mv);
#pragma unroll
  for (int o = 1; o <= 4; o <<= 1) se += __shfl_xor(se, o, 64);
  if (eg == 0 && valid) {
    float ls = mv + __logf(se);
    float4 r0 = make_float4(v0 - ls, v1 - ls, v2 - ls, v3 - ls);
    float4 r1 = make_float4(v4 - ls, v5 - ls, v6 - ls, v7 - ls);
    float4* wp = (float4*)(out + (size_t)node * 40 + fg * 8);
    wp[0] = r0;
    wp[1] = r1;
  }
}

extern "C" void kernel_launch(void* const* d_in, const int* in_sizes, int n_in,
                              void* d_out, int out_size, void* d_ws, size_t ws_size,
                              hipStream_t stream) {
  const float* x = (const float*)d_in[0];
  const int* esrc = (const int*)d_in[1];
  const int* edst = (const int*)d_in[2];
  const float* eval = (const float*)d_in[3];
  const float* W1 = (const float*)d_in[4];
  const float* b1 = (const float*)d_in[5];
  const float* Wr1 = (const float*)d_in[6];
  const float* br1 = (const float*)d_in[7];
  const float* W2 = (const float*)d_in[8];
  const float* b2 = (const float*)d_in[9];
  const float* Wr2 = (const float*)d_in[10];
  const float* br2 = (const float*)d_in[11];
  float* out = (float*)d_out;

  char* ws = (char*)d_ws;
  uint16_t* S1b  = (uint16_t*)(ws);              // 12,800,000
  uint16_t* h    = (uint16_t*)(ws + 12800000);   // 25,600,000
  uint16_t* WT1  = (uint16_t*)(ws + 38400000);   //    262,144
  uint16_t* WT2  = (uint16_t*)(ws + 38662144);   //     65,536
  uint16_t* S2b  = (uint16_t*)(ws + 38727680);   //  6,400,000 (64-padded)
  float*    oacc = (float*)(ws + 45127680);      // 12,800,000 (64-padded)
  int*      counts = (int*)(ws + 57927680);      //    200,000
  int*      cursor = (int*)(ws + 58127680);      //    200,000
  int*      offs   = (int*)(ws + 58327680);      //    200,004
  int2*     es     = (int2*)(ws + 58527744);     //  6,400,000
  int*      blocksums = (int*)(ws + 64927744);   //        784  (total ~64.93 MB)

  hipMemsetAsync(counts, 0, 400000, stream);  // counts + cursor (adjacent)

  k_prep_w1<<<(256 * 512) / 256, 256, 0, stream>>>(W1, Wr1, WT1);
  k_prep_w2<<<(128 * 256) / 256, 256, 0, stream>>>(W2, Wr2, WT2);

  k_hist<<<(N_EDGES + 255) / 256, 256, 0, stream>>>(edst, counts);
  k_blocksum<<<NB, 256, 0, stream>>>(counts, blocksums);
  k_scan2<<<NB, 256, 0, stream>>>(counts, blocksums, offs);
  k_scatter<<<(N_EDGES + 255) / 256, 256, 0, stream>>>(esrc, edst, eval, offs, cursor, es);

  k_gemm1_fused<<<391, 512, 0, stream>>>(x, WT1, S1b, h, br1);

  k_spmm1_csr<<<(N_NODES + 3) / 4, 256, 0, stream>>>(offs, es, S1b, b1, h);

  k_gemm2<<<391, 256, 0, stream>>>(h, WT2, N_NODES, S2b, oacc, b2, br2);

  k_spmm2_lsm<<<(N_NODES + 3) / 4, 256, 0, stream>>>(offs, es, S2b, oacc, out);
}